// Round 14
// baseline (230.254 us; speedup 1.0000x reference)
//
#include <hip/hip_runtime.h>
#include <hip/hip_bf16.h>

typedef __attribute__((ext_vector_type(8))) __bf16 bf16x8;
typedef __attribute__((ext_vector_type(4))) __bf16 bf16x4;
typedef __attribute__((ext_vector_type(2))) __bf16 bf16x2;
typedef __attribute__((ext_vector_type(4))) float f32x4;
typedef __attribute__((ext_vector_type(16))) float f32x16;

#define T_TOK 2048
#define NH 32
#define NKV 4
#define HD 128
#define HID 2048
#define QKV_N 5120   // (32 + 2*4) * 128
#define QSZ 4096     // 32*128
#define KOFF 4096
#define VOFF 4608
#define ATT_N 4096

#define GLOAD_LDS16(g, l)                                              \
  __builtin_amdgcn_global_load_lds(                                    \
      (const __attribute__((address_space(1))) void*)(g),              \
      (__attribute__((address_space(3))) void*)(l), 16, 0, 0)

// ===== fused prep: cast hs | transpose wqkv | transpose wo | rope table ====
__global__ __launch_bounds__(256) void prep(const float* __restrict__ hs,
                                            __bf16* __restrict__ hsb,
                                            const float* __restrict__ wqkv,
                                            __bf16* __restrict__ wqkvT,
                                            const float* __restrict__ wo,
                                            __bf16* __restrict__ woT,
                                            const int* __restrict__ positions,
                                            float* __restrict__ tab) {
  __shared__ __attribute__((aligned(16))) __bf16 tile[64][72];  // [c][r]
  int idx = blockIdx.x;
  if (idx < 4096) {
    int i = idx * 256 + threadIdx.x;
    float4 v = reinterpret_cast<const float4*>(hs)[i];
    bf16x4 o;
    o[0] = (__bf16)v.x; o[1] = (__bf16)v.y; o[2] = (__bf16)v.z; o[3] = (__bf16)v.w;
    reinterpret_cast<bf16x4*>(hsb)[i] = o;
    return;
  }
  idx -= 4096;
  if (idx >= 4608) {
    int j = idx - 4608;
    int t = j * 4 + (threadIdx.x >> 6);
    int d = threadIdx.x & 63;
    float freq = exp2f(-(float)d * 0.20762050593046015f);
    float fr = (float)positions[t] * freq;
    float c, s;
    sincosf(fr, &s, &c);
    tab[t * 128 + d] = c;
    tab[t * 128 + 64 + d] = s;
    return;
  }
  const float* in;
  __bf16* out;
  int R, C, bx, by;
  if (idx < 2560) { in = wqkv; out = wqkvT; R = HID; C = QKV_N; bx = idx % 80; by = idx / 80; }
  else { int j = idx - 2560; in = wo; out = woT; R = QSZ; C = HID; bx = j % 32; by = j / 32; }
  const int c0 = bx * 64;
  const int r0 = by * 64;
  const int ca = (threadIdx.x & 15) * 4;
  const int ra = (threadIdx.x >> 4) * 4;
  float4 v[4];
#pragma unroll
  for (int i = 0; i < 4; ++i)
    v[i] = *reinterpret_cast<const float4*>(&in[(size_t)(r0 + ra + i) * C + c0 + ca]);
#pragma unroll
  for (int j = 0; j < 4; ++j) {
    bf16x4 o;
#pragma unroll
    for (int i = 0; i < 4; ++i) o[i] = (__bf16)(((const float*)&v[i])[j]);
    *reinterpret_cast<bf16x4*>(&tile[ca + j][ra]) = o;
  }
  __syncthreads();
#pragma unroll
  for (int i = 0; i < 2; ++i) {
    int c = i * 32 + (threadIdx.x >> 3);
    int r8 = (threadIdx.x & 7) * 8;
    bf16x8 o = *reinterpret_cast<const bf16x8*>(&tile[c][r8]);
    *reinterpret_cast<bf16x8*>(&out[(size_t)(c0 + c) * R + r0 + r8]) = o;
  }
}

// ====== GEMM v9: C = A*B^T; MODE 0 = bf16 C, MODE 1 = bf16 split-K partials =
template <int MODE>
__global__ __launch_bounds__(256) void gemm_v9(const __bf16* __restrict__ A,
                                               const __bf16* __restrict__ B,
                                               void* __restrict__ Cp,
                                               int M, int N, int Ktot, int KS,
                                               int nby, int nks) {
  __shared__ __attribute__((aligned(16))) __bf16 As[3][128][32];
  __shared__ __attribute__((aligned(16))) __bf16 Bs[3][128][32];
  const int tid = threadIdx.x;
  const int lane = tid & 63;
  const int wave = tid >> 6;
  const int la = lane & 15;
  const int lb = lane >> 4;
  const int wr = (wave >> 1) * 64;
  const int wc = (wave & 1) * 64;

  const int nwg = gridDim.x;
  const int cpx = nwg >> 3;
  const int swz = ((int)blockIdx.x & 7) * cpx + ((int)blockIdx.x >> 3);
  const int ks = swz % nks;
  const int t2 = swz / nks;
  const int by = t2 % nby;
  const int bx = t2 / nby;
  const int rowA0 = by * 128;
  const int rowB0 = bx * 128;
  const int k00 = ks * KS;

  const int srow = wave * 16 + (lane >> 2);
  const int scol = (((lane & 3) * 16) ^ (((lane >> 2) & 3) << 4)) >> 1;
  const __bf16* Asrc0 = &A[(size_t)(rowA0 + srow) * Ktot + k00 + scol];
  const __bf16* Asrc1 = &A[(size_t)(rowA0 + 64 + srow) * Ktot + k00 + scol];
  const __bf16* Bsrc0 = &B[(size_t)(rowB0 + srow) * Ktot + k00 + scol];
  const __bf16* Bsrc1 = &B[(size_t)(rowB0 + 64 + srow) * Ktot + k00 + scol];

#define STAGEG(b, k0)                                            \
  do {                                                           \
    GLOAD_LDS16(Asrc0 + (k0), &As[b][wave * 16][0]);             \
    GLOAD_LDS16(Asrc1 + (k0), &As[b][64 + wave * 16][0]);        \
    GLOAD_LDS16(Bsrc0 + (k0), &Bs[b][wave * 16][0]);             \
    GLOAD_LDS16(Bsrc1 + (k0), &Bs[b][64 + wave * 16][0]);        \
  } while (0)

  f32x4 acc[4][4] = {};

  const int nt = KS >> 5;
  STAGEG(0, 0);
  STAGEG(1, 32);
  asm volatile("s_waitcnt vmcnt(4)" ::: "memory");
  __builtin_amdgcn_s_barrier();
  __builtin_amdgcn_sched_barrier(0);

  const int rdswz = (lb * 16) ^ ((la & 3) << 4);

  int cur = 0, stg = 2;
  for (int t = 0; t < nt; ++t) {
    if (t + 2 < nt) {
      STAGEG(stg, (t + 2) * 32);
    }

    const char* Ab = (const char*)&As[cur][0][0];
    const char* Bb = (const char*)&Bs[cur][0][0];
    bf16x8 af[4], bfr[4];
#pragma unroll
    for (int m = 0; m < 4; ++m)
      af[m] = *reinterpret_cast<const bf16x8*>(Ab + (wr + m * 16 + la) * 64 + rdswz);
#pragma unroll
    for (int n = 0; n < 4; ++n)
      bfr[n] = *reinterpret_cast<const bf16x8*>(Bb + (wc + n * 16 + la) * 64 + rdswz);
    __builtin_amdgcn_s_setprio(1);
#pragma unroll
    for (int m = 0; m < 4; ++m)
#pragma unroll
      for (int n = 0; n < 4; ++n)
        acc[m][n] = __builtin_amdgcn_mfma_f32_16x16x32_bf16(af[m], bfr[n], acc[m][n], 0, 0, 0);
    __builtin_amdgcn_s_setprio(0);

    const int rem = nt - 1 - t;
    if (rem >= 2) {
      asm volatile("s_waitcnt vmcnt(4)" ::: "memory");
    } else if (rem == 1) {
      asm volatile("s_waitcnt vmcnt(0)" ::: "memory");
    }
    if (rem) {
      __builtin_amdgcn_sched_barrier(0);
      __builtin_amdgcn_s_barrier();
      __builtin_amdgcn_sched_barrier(0);
    }
    cur = (cur == 2) ? 0 : cur + 1;
    stg = (stg == 2) ? 0 : stg + 1;
  }
#undef STAGEG

#pragma unroll
  for (int m = 0; m < 4; ++m) {
#pragma unroll
    for (int n = 0; n < 4; ++n) {
#pragma unroll
      for (int r = 0; r < 4; ++r) {
        int row = rowA0 + wr + m * 16 + lb * 4 + r;
        int col = rowB0 + wc + n * 16 + la;
        if (MODE == 1) {
          __bf16* pp = (__bf16*)Cp + (size_t)ks * M * N;
          pp[(size_t)row * N + col] = (__bf16)acc[m][n][r];
        } else {
          reinterpret_cast<__bf16*>(Cp)[(size_t)row * N + col] = (__bf16)acc[m][n][r];
        }
      }
    }
  }
}

// ---- split-K reduce: out[i] = (f32)p0[i] + (f32)p1[i], bf16 partials ------
__global__ __launch_bounds__(256) void reduce2_bf(const __bf16* __restrict__ pp,
                                                  float* __restrict__ out, int n8) {
  int i = blockIdx.x * 256 + threadIdx.x;
  if (i < n8) {
    bf16x8 a = reinterpret_cast<const bf16x8*>(pp)[i];
    bf16x8 b = reinterpret_cast<const bf16x8*>(pp + (size_t)HID * T_TOK)[i];
    float4 o0, o1;
    o0.x = (float)a[0] + (float)b[0];
    o0.y = (float)a[1] + (float)b[1];
    o0.z = (float)a[2] + (float)b[2];
    o0.w = (float)a[3] + (float)b[3];
    o1.x = (float)a[4] + (float)b[4];
    o1.y = (float)a[5] + (float)b[5];
    o1.z = (float)a[6] + (float)b[6];
    o1.w = (float)a[7] + (float)b[7];
    reinterpret_cast<float4*>(out)[2 * i] = o0;
    reinterpret_cast<float4*>(out)[2 * i + 1] = o1;
  }
}

// ===== fused post-QKV: RMSNorm+RoPE (q,k) | V transpose =====================
__global__ __launch_bounds__(256) void postqkv(__bf16* __restrict__ qkv,
                                               __bf16* __restrict__ vt,
                                               const float* __restrict__ tab,
                                               const float* __restrict__ qw,
                                               const float* __restrict__ kw) {
  __shared__ __bf16 tile[64][72];
  int idx = blockIdx.x;
  if (idx < 18432) {
    const int t = idx & 2047;
    const int hg = idx >> 11;
    const int wave = threadIdx.x >> 6;
    const int lane = threadIdx.x & 63;
    const int head = hg * 4 + wave;
    const bool is_q = head < NH;
    const int col = is_q ? head * HD : KOFF + (head - NH) * HD;
    __bf16* row = qkv + (size_t)t * QKV_N + col;

    bf16x2 v = *reinterpret_cast<const bf16x2*>(&row[lane * 2]);
    float x0 = (float)v[0], x1 = (float)v[1];
    float ss = x0 * x0 + x1 * x1;
#pragma unroll
    for (int mm = 1; mm < 64; mm <<= 1) ss += __shfl_xor(ss, mm);
    float sc = rsqrtf(ss * (1.0f / 128.0f) + 1e-6f);
    const float* wv = is_q ? qw : kw;
    float y0 = x0 * sc * wv[lane * 2];
    float y1 = x1 * sc * wv[lane * 2 + 1];
    float o0 = __shfl_xor(y0, 32);
    float o1 = __shfl_xor(y1, 32);
    const int dbase = (lane & 31) * 2;
    float c0 = tab[t * 128 + dbase], c1 = tab[t * 128 + dbase + 1];
    float s0 = tab[t * 128 + 64 + dbase], s1 = tab[t * 128 + 64 + dbase + 1];
    float r0, r1;
    if (lane < 32) { r0 = y0 * c0 - o0 * s0; r1 = y1 * c1 - o1 * s1; }
    else           { r0 = y0 * c0 + o0 * s0; r1 = y1 * c1 + o1 * s1; }
    bf16x2 ov;
    ov[0] = (__bf16)r0;
    ov[1] = (__bf16)r1;
    *reinterpret_cast<bf16x2*>(&row[lane * 2]) = ov;
    return;
  }
  const int j = idx - 18432;
  const int t0 = (j & 31) * 64;
  const int d0 = ((j >> 5) & 1) * 64;
  const int kvh = j >> 6;
  const int tx = threadIdx.x & 63;
  const int ty = threadIdx.x >> 6;
#pragma unroll
  for (int i = 0; i < 64; i += 4)
    tile[ty + i][tx] = qkv[(size_t)(t0 + ty + i) * QKV_N + VOFF + kvh * HD + d0 + tx];
  __syncthreads();
#pragma unroll
  for (int i = 0; i < 64; i += 4)
    vt[((size_t)kvh * HD + d0 + ty + i) * T_TOK + t0 + tx] = tile[tx][ty + i];
}

// ===== flash attention v8: flash5 inner loop, K single-buffer (48KB LDS =
// 3 blocks/CU), split-KV across blocks for qt>=32 with cross-block merge. ====
__device__ __forceinline__ uint32_t pkbf(float a, float b) {
  union { __bf16 h; unsigned short u; } x, y;
  x.h = (__bf16)a;
  y.h = (__bf16)b;
  return (uint32_t)x.u | ((uint32_t)y.u << 16);
}

__global__ __launch_bounds__(256, 3) void flash_attn8(const __bf16* __restrict__ qkv,
                                                      const __bf16* __restrict__ vt,
                                                      __bf16* __restrict__ attn,
                                                      __bf16* __restrict__ pO,
                                                      float2* __restrict__ ml) {
  // 48KB: K[64][128] @0 (16KB) | Vd0 [128][64] @8192 | Vd1 @16384 (elements)
  __shared__ __attribute__((aligned(16))) __bf16 lds[24576];

  const int tid = threadIdx.x;
  const int lane = tid & 63;
  const int wave = tid >> 6;     // 0..3
  const int q5 = lane & 31;
  const int hi = lane >> 5;
  const int yy = blockIdx.x;     // 0..7
  const int kvh = yy >> 1;
  const int h = kvh * 8 + (yy & 1) * 4 + wave;
  const __bf16* Kbase = qkv + KOFF + kvh * HD;
  const __bf16* Vbase = vt + (size_t)kvh * HD * T_TOK;

  int qt, part;
  {
    const int y = blockIdx.y;    // 0..95, heavy first
    if (y < 64) { qt = 63 - (y >> 1); part = y & 1; }   // qt 63..32, 2 parts
    else        { qt = 95 - y;        part = -1;     }  // qt 31..0, full
  }
  const int qb = qt * 32;
  const int qrow = qb + q5;
  const int nt = (qb + 95) >> 6;         // ceil((qt+1)/2)
  int t0 = 0, t1 = nt;
  if (part >= 0) { const int nh = nt >> 1; if (part) t0 = nh; else t1 = nh; }

  const float qscale = 0.088388347648318447f * 1.4426950408889634f;

  bf16x8 qf[8];
  {
    const __bf16* Qp = qkv + (size_t)(qb + q5) * QKV_N + h * HD + hi * 8;
#pragma unroll
    for (int k0 = 0; k0 < 8; ++k0) {
      bf16x8 q = *reinterpret_cast<const bf16x8*>(Qp + k0 * 16);
#pragma unroll
      for (int j = 0; j < 8; ++j) q[j] = (__bf16)((float)q[j] * qscale);
      qf[k0] = q;
    }
  }

  const int kc = (lane & 15) * 16;
  const int vc = (lane & 7) * 16;

#define STAGEK(kv00)                                                     \
  do {                                                                   \
    _Pragma("unroll")                                                    \
    for (int i = 0; i < 4; ++i) {                                        \
      int kr = wave * 16 + i * 4 + (lane >> 4);                          \
      int ksc = (kc ^ ((kr & 15) << 4)) >> 1;                            \
      GLOAD_LDS16(Kbase + (size_t)((kv00) + kr) * QKV_N + ksc,           \
                  lds + (wave * 16 + i * 4) * 128);                      \
    }                                                                    \
  } while (0)
#define STAGEV(kv00, par)                                                \
  do {                                                                   \
    __bf16* vdst = lds + 8192 + (par) * 8192;                            \
    _Pragma("unroll")                                                    \
    for (int i = 0; i < 4; ++i) {                                        \
      int vr = wave * 32 + i * 8 + (lane >> 3);                          \
      int vsc = (vc ^ ((vr & 7) << 4)) >> 1;                             \
      GLOAD_LDS16(Vbase + (size_t)vr * T_TOK + (kv00) + vsc,             \
                  vdst + (wave * 32 + i * 8) * 64);                      \
    }                                                                    \
  } while (0)

  f32x16 acc0 = {}, acc1 = {}, acc2 = {}, acc3 = {};
  float mrow = -1e30f, lrow = 0.0f;

  STAGEK(t0 * 64);
  STAGEV(t0 * 64, t0 & 1);
  asm volatile("s_waitcnt vmcnt(0)" ::: "memory");
  __builtin_amdgcn_s_barrier();
  __builtin_amdgcn_sched_barrier(0);

  for (int t = t0; t < t1; ++t) {
    const int kv0 = t * 64;
    const char* Kt = (const char*)lds;
    const char* Vt = (const char*)lds + 16384 + (t & 1) * 16384;

    // ---- QK^T from single K buffer ----
    f32x16 st0 = {}, st1 = {};
    __builtin_amdgcn_s_setprio(1);
#pragma unroll
    for (int k0 = 0; k0 < 8; ++k0) {
      int cS = (k0 * 32 + hi * 16) ^ ((q5 & 15) << 4);
      bf16x8 a0 = *reinterpret_cast<const bf16x8*>(Kt + q5 * 256 + cS);
      bf16x8 a1 = *reinterpret_cast<const bf16x8*>(Kt + (32 + q5) * 256 + cS);
      st0 = __builtin_amdgcn_mfma_f32_32x32x16_bf16(a0, qf[k0], st0, 0, 0, 0);
      st1 = __builtin_amdgcn_mfma_f32_32x32x16_bf16(a1, qf[k0], st1, 0, 0, 0);
    }
    __builtin_amdgcn_s_setprio(0);

    __builtin_amdgcn_sched_barrier(0);
    __builtin_amdgcn_s_barrier();          // all waves done reading K
    __builtin_amdgcn_sched_barrier(0);
    if (t + 1 < t1) {                      // stage next K (single) + V (dbuf)
      STAGEK((t + 1) * 64);
      STAGEV((t + 1) * 64, (t + 1) & 1);
    }

    // ---- mask (diagonal region only) ----
    if (!(kv0 + 63 <= qb)) {
#pragma unroll
      for (int r = 0; r < 16; ++r) {
        int kp = kv0 + (r & 3) + 8 * (r >> 2) + 4 * hi;
        if (kp > qrow) st0[r] = -1e30f;
        if (kp + 32 > qrow) st1[r] = -1e30f;
      }
    }
    // ---- tree max ----
    float tm[16];
#pragma unroll
    for (int r = 0; r < 16; ++r) tm[r] = fmaxf(st0[r], st1[r]);
#pragma unroll
    for (int s = 8; s > 0; s >>= 1)
#pragma unroll
      for (int r = 0; r < s; ++r) tm[r] = fmaxf(tm[r], tm[r + s]);
    float mx = fmaxf(tm[0], __shfl_xor(tm[0], 32));
    if (__any(mx > mrow + 8.0f)) {
      float mnew = fmaxf(mrow, mx);
      float corr = exp2f(mrow - mnew);
      lrow *= corr;
      acc0 *= corr; acc1 *= corr; acc2 *= corr; acc3 *= corr;
      mrow = mnew;
    }
    // ---- exp2 + tree sum ----
    float sv[16];
#pragma unroll
    for (int r = 0; r < 16; ++r) {
      float p0 = exp2f(st0[r] - mrow);
      float p1 = exp2f(st1[r] - mrow);
      sv[r] = p0 + p1;
      st0[r] = p0;
      st1[r] = p1;
    }
#pragma unroll
    for (int s = 8; s > 0; s >>= 1)
#pragma unroll
      for (int r = 0; r < s; ++r) sv[r] += sv[r + s];
    lrow += sv[0] + __shfl_xor(sv[0], 32);

    uint32_t W0[8], W1[8];
#pragma unroll
    for (int m = 0; m < 8; ++m) {
      W0[m] = pkbf(st0[2 * m], st0[2 * m + 1]);
      W1[m] = pkbf(st1[2 * m], st1[2 * m + 1]);
    }

    // ---- PV from V dbuf ----
    const bool hib = (hi != 0);
#pragma unroll
    for (int ks = 0; ks < 4; ++ks) {
      const int j = 4 * (ks & 1);
      uint32_t wj0, wj1, wj2, wj3;
      if (ks < 2) { wj0 = W0[j]; wj1 = W0[j + 1]; wj2 = W0[j + 2]; wj3 = W0[j + 3]; }
      else        { wj0 = W1[j]; wj1 = W1[j + 1]; wj2 = W1[j + 2]; wj3 = W1[j + 3]; }
      uint32_t keepA = hib ? wj2 : wj0;
      uint32_t keepB = hib ? wj3 : wj1;
      uint32_t sendA = hib ? wj0 : wj2;
      uint32_t sendB = hib ? wj1 : wj3;
      uint32_t recvA = (uint32_t)__shfl_xor((int)sendA, 32);
      uint32_t recvB = (uint32_t)__shfl_xor((int)sendB, 32);
      union { uint32_t u[4]; bf16x8 v; } fr;
      fr.u[0] = hib ? recvA : keepA;
      fr.u[1] = hib ? recvB : keepB;
      fr.u[2] = hib ? keepA : recvA;
      fr.u[3] = hib ? keepB : recvB;
      const int cV = (ks * 32 + hi * 16) ^ ((q5 & 7) << 4);
      __builtin_amdgcn_s_setprio(1);
      bf16x8 v0 = *reinterpret_cast<const bf16x8*>(Vt + (0 * 32 + q5) * 128 + cV);
      acc0 = __builtin_amdgcn_mfma_f32_32x32x16_bf16(v0, fr.v, acc0, 0, 0, 0);
      bf16x8 v1 = *reinterpret_cast<const bf16x8*>(Vt + (1 * 32 + q5) * 128 + cV);
      acc1 = __builtin_amdgcn_mfma_f32_32x32x16_bf16(v1, fr.v, acc1, 0, 0, 0);
      bf16x8 v2 = *reinterpret_cast<const bf16x8*>(Vt + (2 * 32 + q5) * 128 + cV);
      acc2 = __builtin_amdgcn_mfma_f32_32x32x16_bf16(v2, fr.v, acc2, 0, 0, 0);
      bf16x8 v3 = *reinterpret_cast<const bf16x8*>(Vt + (3 * 32 + q5) * 128 + cV);
      acc3 = __builtin_amdgcn_mfma_f32_32x32x16_bf16(v3, fr.v, acc3, 0, 0, 0);
      __builtin_amdgcn_s_setprio(0);
    }
    if (t + 1 < t1) {
      asm volatile("s_waitcnt vmcnt(0)" ::: "memory");  // next K,V landed
    }
    __builtin_amdgcn_sched_barrier(0);
    __builtin_amdgcn_s_barrier();
    __builtin_amdgcn_sched_barrier(0);
  }
#undef STAGEK
#undef STAGEV

  // ---- epilogue: per-wave LDS transpose, store to attnb or partials ----
  __syncthreads();
  {
    char* ob = (char*)lds + wave * 8192;   // 32KB of the 48KB
    const int swzE = (q5 & 15) << 4;
    const float sc = (part < 0) ? (1.0f / lrow) : 1.0f;
#pragma unroll
    for (int dt = 0; dt < 4; ++dt) {
      f32x16 a = dt == 0 ? acc0 : dt == 1 ? acc1 : dt == 2 ? acc2 : acc3;
#pragma unroll
      for (int t4 = 0; t4 < 4; ++t4) {
        uint2 wv;
        wv.x = pkbf(a[4 * t4] * sc, a[4 * t4 + 1] * sc);
        wv.y = pkbf(a[4 * t4 + 2] * sc, a[4 * t4 + 3] * sc);
        int d2 = (dt * 32 + 8 * t4 + 4 * hi) * 2;
        *reinterpret_cast<uint2*>(ob + q5 * 256 + (d2 ^ swzE)) = wv;
      }
    }
    if (part < 0) {
#pragma unroll
      for (int rr = 0; rr < 8; ++rr) {
        int idx = rr * 64 + lane;
        int q = idx >> 4;
        int cc = (idx & 15) * 16;
        bf16x8 o = *reinterpret_cast<const bf16x8*>(ob + q * 256 + (cc ^ ((q & 15) << 4)));
        *reinterpret_cast<bf16x8*>(&attn[(size_t)(qb + q) * ATT_N + h * HD + (cc >> 1)]) = o;
      }
    } else {
      const int pq = qt - 32;
      const size_t slot = ((size_t)(part * 32 + pq) * NH + h) * 32;
      __bf16* pb = pO + slot * 128;
#pragma unroll
      for (int rr = 0; rr < 8; ++rr) {
        int idx = rr * 64 + lane;
        int q = idx >> 4;
        int cc = (idx & 15) * 16;
        bf16x8 o = *reinterpret_cast<const bf16x8*>(ob + q * 256 + (cc ^ ((q & 15) << 4)));
        *reinterpret_cast<bf16x8*>(&pb[(size_t)q * 128 + (cc >> 1)]) = o;
      }
      if (hi == 0) ml[slot + q5] = make_float2(mrow, lrow);
    }
  }
}

// ---- merge the two KV-halves for qt>=32: attnb = (O0*w0 + O1*w1)/denom ----
__global__ __launch_bounds__(256) void merge_attn(const __bf16* __restrict__ pO,
                                                  const float2* __restrict__ ml,
                                                  __bf16* __restrict__ attn) {
  const int b = blockIdx.x;        // 0..1023
  const int pq = b >> 5;
  const int h = b & 31;
  const int q = threadIdx.x >> 3;          // 0..31
  const int dd = (threadIdx.x & 7) * 16;   // 0..112
  const size_t s0 = ((size_t)pq * NH + h) * 32 + q;
  const size_t s1 = ((size_t)(32 + pq) * NH + h) * 32 + q;
  float2 a0 = ml[s0];
  float2 a1 = ml[s1];
  float M = fmaxf(a0.x, a1.x);
  float w0 = exp2f(a0.x - M);
  float w1 = exp2f(a1.x - M);
  float inv = 1.0f / (a0.y * w0 + a1.y * w1);
  w0 *= inv;
  w1 *= inv;
  bf16x8 x0a = *reinterpret_cast<const bf16x8*>(&pO[s0 * 128 + dd]);
  bf16x8 x0b = *reinterpret_cast<const bf16x8*>(&pO[s0 * 128 + dd + 8]);
  bf16x8 x1a = *reinterpret_cast<const bf16x8*>(&pO[s1 * 128 + dd]);
  bf16x8 x1b = *reinterpret_cast<const bf16x8*>(&pO[s1 * 128 + dd + 8]);
  bf16x8 oa, obv;
#pragma unroll
  for (int j = 0; j < 8; ++j) {
    oa[j] = (__bf16)((float)x0a[j] * w0 + (float)x1a[j] * w1);
    obv[j] = (__bf16)((float)x0b[j] * w0 + (float)x1b[j] * w1);
  }
  const int row = (pq + 32) * 32 + q;
  __bf16* dst = attn + (size_t)row * ATT_N + h * HD + dd;
  *reinterpret_cast<bf16x8*>(dst) = oa;
  *reinterpret_cast<bf16x8*>(dst + 8) = obv;
}

extern "C" void kernel_launch(void* const* d_in, const int* in_sizes, int n_in,
                              void* d_out, int out_size, void* d_ws, size_t ws_size,
                              hipStream_t stream) {
  const float* hs   = (const float*)d_in[0];
  const int*   pos  = (const int*)d_in[1];
  const float* wqkv = (const float*)d_in[2];
  const float* wo   = (const float*)d_in[3];
  const float* qw   = (const float*)d_in[4];
  const float* kw   = (const float*)d_in[5];
  float* out = (float*)d_out;

  char* p = (char*)d_ws;
  __bf16* hsb   = (__bf16*)p; p += (size_t)T_TOK * HID * 2;
  __bf16* wqkvT = (__bf16*)p; p += (size_t)QKV_N * HID * 2;
  __bf16* woT   = (__bf16*)p; p += (size_t)HID * QSZ * 2;
  __bf16* qkvb  = (__bf16*)p; p += (size_t)T_TOK * QKV_N * 2;
  __bf16* attnb = (__bf16*)p; p += (size_t)T_TOK * QSZ * 2;
  __bf16* vtb   = (__bf16*)p; p += (size_t)NKV * HD * T_TOK * 2;
  float*  ropet = (float*)p;  p += (size_t)T_TOK * HD * 4;
  __bf16* oprt  = (__bf16*)p; p += (size_t)2 * T_TOK * HID * 2;   // split-K partials
  __bf16* pOb   = (__bf16*)p; p += (size_t)2 * 32 * NH * 32 * 128 * 2;  // 16.8MB
  float2* mlb   = (float2*)p; p += (size_t)2 * 32 * NH * 32 * sizeof(float2);

  // 1. fused prep
  prep<<<9216, 256, 0, stream>>>(hs, hsb, wqkv, wqkvT, wo, woT, pos, ropet);
  // 2. QKV projection
  gemm_v9<0><<<(QKV_N / 128) * (T_TOK / 128), 256, 0, stream>>>(
      hsb, wqkvT, qkvb, T_TOK, QKV_N, HID, HID, T_TOK / 128, 1);
  // 3. fused RMSNorm+RoPE | V transpose
  postqkv<<<18688, 256, 0, stream>>>(qkvb, vtb, ropet, qw, kw);
  // 4. flash attention (balanced split-KV, 3 blocks/CU) + merge
  flash_attn8<<<dim3(8, 96), 256, 0, stream>>>(qkvb, vtb, attnb, pOb, mlb);
  merge_attn<<<1024, 256, 0, stream>>>(pOb, mlb, attnb);
  // 5. O projection, split-K=2 (bf16 partials) + reduce
  gemm_v9<1><<<2 * (HID / 128) * (T_TOK / 128), 256, 0, stream>>>(
      attnb, woT, oprt, T_TOK, HID, QSZ, QSZ / 2, T_TOK / 128, 2);
  reduce2_bf<<<(T_TOK * HID / 8 + 255) / 256, 256, 0, stream>>>(
      oprt, out, T_TOK * HID / 8);
}

// Round 16
// 222.742 us; speedup vs baseline: 1.0337x; 1.0337x over previous
//
#include <hip/hip_runtime.h>
#include <hip/hip_bf16.h>

typedef __attribute__((ext_vector_type(8))) __bf16 bf16x8;
typedef __attribute__((ext_vector_type(4))) __bf16 bf16x4;
typedef __attribute__((ext_vector_type(2))) __bf16 bf16x2;
typedef __attribute__((ext_vector_type(4))) float f32x4;
typedef __attribute__((ext_vector_type(16))) float f32x16;
typedef __attribute__((ext_vector_type(2))) unsigned int uint32x2;

#define T_TOK 2048
#define NH 32
#define NKV 4
#define HD 128
#define HID 2048
#define QKV_N 5120   // (32 + 2*4) * 128
#define QSZ 4096     // 32*128
#define KOFF 4096
#define VOFF 4608
#define ATT_N 4096

#define GLOAD_LDS16(g, l)                                              \
  __builtin_amdgcn_global_load_lds(                                    \
      (const __attribute__((address_space(1))) void*)(g),              \
      (__attribute__((address_space(3))) void*)(l), 16, 0, 0)

// ===== fused prep: cast hs | transpose wqkv | transpose wo | rope table ====
__global__ __launch_bounds__(256) void prep(const float* __restrict__ hs,
                                            __bf16* __restrict__ hsb,
                                            const float* __restrict__ wqkv,
                                            __bf16* __restrict__ wqkvT,
                                            const float* __restrict__ wo,
                                            __bf16* __restrict__ woT,
                                            const int* __restrict__ positions,
                                            float* __restrict__ tab) {
  __shared__ __attribute__((aligned(16))) __bf16 tile[64][72];  // [c][r]
  int idx = blockIdx.x;
  if (idx < 4096) {
    int i = idx * 256 + threadIdx.x;
    float4 v = reinterpret_cast<const float4*>(hs)[i];
    bf16x4 o;
    o[0] = (__bf16)v.x; o[1] = (__bf16)v.y; o[2] = (__bf16)v.z; o[3] = (__bf16)v.w;
    reinterpret_cast<bf16x4*>(hsb)[i] = o;
    return;
  }
  idx -= 4096;
  if (idx >= 4608) {
    int j = idx - 4608;
    int t = j * 4 + (threadIdx.x >> 6);
    int d = threadIdx.x & 63;
    float freq = exp2f(-(float)d * 0.20762050593046015f);
    float fr = (float)positions[t] * freq;
    float c, s;
    sincosf(fr, &s, &c);
    tab[t * 128 + d] = c;
    tab[t * 128 + 64 + d] = s;
    return;
  }
  const float* in;
  __bf16* out;
  int R, C, bx, by;
  if (idx < 2560) { in = wqkv; out = wqkvT; R = HID; C = QKV_N; bx = idx % 80; by = idx / 80; }
  else { int j = idx - 2560; in = wo; out = woT; R = QSZ; C = HID; bx = j % 32; by = j / 32; }
  const int c0 = bx * 64;
  const int r0 = by * 64;
  const int ca = (threadIdx.x & 15) * 4;
  const int ra = (threadIdx.x >> 4) * 4;
  float4 v[4];
#pragma unroll
  for (int i = 0; i < 4; ++i)
    v[i] = *reinterpret_cast<const float4*>(&in[(size_t)(r0 + ra + i) * C + c0 + ca]);
#pragma unroll
  for (int j = 0; j < 4; ++j) {
    bf16x4 o;
#pragma unroll
    for (int i = 0; i < 4; ++i) o[i] = (__bf16)(((const float*)&v[i])[j]);
    *reinterpret_cast<bf16x4*>(&tile[ca + j][ra]) = o;
  }
  __syncthreads();
#pragma unroll
  for (int i = 0; i < 2; ++i) {
    int c = i * 32 + (threadIdx.x >> 3);
    int r8 = (threadIdx.x & 7) * 8;
    bf16x8 o = *reinterpret_cast<const bf16x8*>(&tile[c][r8]);
    *reinterpret_cast<bf16x8*>(&out[(size_t)(c0 + c) * R + r0 + r8]) = o;
  }
}

// ====== GEMM v9: C = A*B^T; MODE 0 = bf16 C, MODE 1 = bf16 split-K partials =
template <int MODE>
__global__ __launch_bounds__(256) void gemm_v9(const __bf16* __restrict__ A,
                                               const __bf16* __restrict__ B,
                                               void* __restrict__ Cp,
                                               int M, int N, int Ktot, int KS,
                                               int nby, int nks) {
  __shared__ __attribute__((aligned(16))) __bf16 As[3][128][32];
  __shared__ __attribute__((aligned(16))) __bf16 Bs[3][128][32];
  const int tid = threadIdx.x;
  const int lane = tid & 63;
  const int wave = tid >> 6;
  const int la = lane & 15;
  const int lb = lane >> 4;
  const int wr = (wave >> 1) * 64;
  const int wc = (wave & 1) * 64;

  const int nwg = gridDim.x;
  const int cpx = nwg >> 3;
  const int swz = ((int)blockIdx.x & 7) * cpx + ((int)blockIdx.x >> 3);
  const int ks = swz % nks;
  const int t2 = swz / nks;
  const int by = t2 % nby;
  const int bx = t2 / nby;
  const int rowA0 = by * 128;
  const int rowB0 = bx * 128;
  const int k00 = ks * KS;

  const int srow = wave * 16 + (lane >> 2);
  const int scol = (((lane & 3) * 16) ^ (((lane >> 2) & 3) << 4)) >> 1;
  const __bf16* Asrc0 = &A[(size_t)(rowA0 + srow) * Ktot + k00 + scol];
  const __bf16* Asrc1 = &A[(size_t)(rowA0 + 64 + srow) * Ktot + k00 + scol];
  const __bf16* Bsrc0 = &B[(size_t)(rowB0 + srow) * Ktot + k00 + scol];
  const __bf16* Bsrc1 = &B[(size_t)(rowB0 + 64 + srow) * Ktot + k00 + scol];

#define STAGEG(b, k0)                                            \
  do {                                                           \
    GLOAD_LDS16(Asrc0 + (k0), &As[b][wave * 16][0]);             \
    GLOAD_LDS16(Asrc1 + (k0), &As[b][64 + wave * 16][0]);        \
    GLOAD_LDS16(Bsrc0 + (k0), &Bs[b][wave * 16][0]);             \
    GLOAD_LDS16(Bsrc1 + (k0), &Bs[b][64 + wave * 16][0]);        \
  } while (0)

  f32x4 acc[4][4] = {};

  const int nt = KS >> 5;
  STAGEG(0, 0);
  STAGEG(1, 32);
  asm volatile("s_waitcnt vmcnt(4)" ::: "memory");
  __builtin_amdgcn_s_barrier();
  __builtin_amdgcn_sched_barrier(0);

  const int rdswz = (lb * 16) ^ ((la & 3) << 4);

  int cur = 0, stg = 2;
  for (int t = 0; t < nt; ++t) {
    if (t + 2 < nt) {
      STAGEG(stg, (t + 2) * 32);
    }

    const char* Ab = (const char*)&As[cur][0][0];
    const char* Bb = (const char*)&Bs[cur][0][0];
    bf16x8 af[4], bfr[4];
#pragma unroll
    for (int m = 0; m < 4; ++m)
      af[m] = *reinterpret_cast<const bf16x8*>(Ab + (wr + m * 16 + la) * 64 + rdswz);
#pragma unroll
    for (int n = 0; n < 4; ++n)
      bfr[n] = *reinterpret_cast<const bf16x8*>(Bb + (wc + n * 16 + la) * 64 + rdswz);
    __builtin_amdgcn_s_setprio(1);
#pragma unroll
    for (int m = 0; m < 4; ++m)
#pragma unroll
      for (int n = 0; n < 4; ++n)
        acc[m][n] = __builtin_amdgcn_mfma_f32_16x16x32_bf16(af[m], bfr[n], acc[m][n], 0, 0, 0);
    __builtin_amdgcn_s_setprio(0);

    const int rem = nt - 1 - t;
    if (rem >= 2) {
      asm volatile("s_waitcnt vmcnt(4)" ::: "memory");
    } else if (rem == 1) {
      asm volatile("s_waitcnt vmcnt(0)" ::: "memory");
    }
    if (rem) {
      __builtin_amdgcn_sched_barrier(0);
      __builtin_amdgcn_s_barrier();
      __builtin_amdgcn_sched_barrier(0);
    }
    cur = (cur == 2) ? 0 : cur + 1;
    stg = (stg == 2) ? 0 : stg + 1;
  }
#undef STAGEG

#pragma unroll
  for (int m = 0; m < 4; ++m) {
#pragma unroll
    for (int n = 0; n < 4; ++n) {
#pragma unroll
      for (int r = 0; r < 4; ++r) {
        int row = rowA0 + wr + m * 16 + lb * 4 + r;
        int col = rowB0 + wc + n * 16 + la;
        if (MODE == 1) {
          __bf16* pp = (__bf16*)Cp + (size_t)ks * M * N;
          pp[(size_t)row * N + col] = (__bf16)acc[m][n][r];
        } else {
          reinterpret_cast<__bf16*>(Cp)[(size_t)row * N + col] = (__bf16)acc[m][n][r];
        }
      }
    }
  }
}

// ---- split-K reduce: out[i] = (f32)p0[i] + (f32)p1[i], bf16 partials ------
__global__ __launch_bounds__(256) void reduce2_bf(const __bf16* __restrict__ pp,
                                                  float* __restrict__ out, int n8) {
  int i = blockIdx.x * 256 + threadIdx.x;
  if (i < n8) {
    bf16x8 a = reinterpret_cast<const bf16x8*>(pp)[i];
    bf16x8 b = reinterpret_cast<const bf16x8*>(pp + (size_t)HID * T_TOK)[i];
    float4 o0, o1;
    o0.x = (float)a[0] + (float)b[0];
    o0.y = (float)a[1] + (float)b[1];
    o0.z = (float)a[2] + (float)b[2];
    o0.w = (float)a[3] + (float)b[3];
    o1.x = (float)a[4] + (float)b[4];
    o1.y = (float)a[5] + (float)b[5];
    o1.z = (float)a[6] + (float)b[6];
    o1.w = (float)a[7] + (float)b[7];
    reinterpret_cast<float4*>(out)[2 * i] = o0;
    reinterpret_cast<float4*>(out)[2 * i + 1] = o1;
  }
}

// ===== fused post-QKV: RMSNorm+RoPE (q,k) | V transpose =====================
__global__ __launch_bounds__(256) void postqkv(__bf16* __restrict__ qkv,
                                               __bf16* __restrict__ vt,
                                               const float* __restrict__ tab,
                                               const float* __restrict__ qw,
                                               const float* __restrict__ kw) {
  __shared__ __bf16 tile[64][72];
  int idx = blockIdx.x;
  if (idx < 18432) {
    const int t = idx & 2047;
    const int hg = idx >> 11;
    const int wave = threadIdx.x >> 6;
    const int lane = threadIdx.x & 63;
    const int head = hg * 4 + wave;
    const bool is_q = head < NH;
    const int col = is_q ? head * HD : KOFF + (head - NH) * HD;
    __bf16* row = qkv + (size_t)t * QKV_N + col;

    bf16x2 v = *reinterpret_cast<const bf16x2*>(&row[lane * 2]);
    float x0 = (float)v[0], x1 = (float)v[1];
    float ss = x0 * x0 + x1 * x1;
#pragma unroll
    for (int mm = 1; mm < 64; mm <<= 1) ss += __shfl_xor(ss, mm);
    float sc = rsqrtf(ss * (1.0f / 128.0f) + 1e-6f);
    const float* wv = is_q ? qw : kw;
    float y0 = x0 * sc * wv[lane * 2];
    float y1 = x1 * sc * wv[lane * 2 + 1];
    float o0 = __shfl_xor(y0, 32);
    float o1 = __shfl_xor(y1, 32);
    const int dbase = (lane & 31) * 2;
    float c0 = tab[t * 128 + dbase], c1 = tab[t * 128 + dbase + 1];
    float s0 = tab[t * 128 + 64 + dbase], s1 = tab[t * 128 + 64 + dbase + 1];
    float r0, r1;
    if (lane < 32) { r0 = y0 * c0 - o0 * s0; r1 = y1 * c1 - o1 * s1; }
    else           { r0 = y0 * c0 + o0 * s0; r1 = y1 * c1 + o1 * s1; }
    bf16x2 ov;
    ov[0] = (__bf16)r0;
    ov[1] = (__bf16)r1;
    *reinterpret_cast<bf16x2*>(&row[lane * 2]) = ov;
    return;
  }
  const int j = idx - 18432;
  const int t0 = (j & 31) * 64;
  const int d0 = ((j >> 5) & 1) * 64;
  const int kvh = j >> 6;
  const int tx = threadIdx.x & 63;
  const int ty = threadIdx.x >> 6;
#pragma unroll
  for (int i = 0; i < 64; i += 4)
    tile[ty + i][tx] = qkv[(size_t)(t0 + ty + i) * QKV_N + VOFF + kvh * HD + d0 + tx];
  __syncthreads();
#pragma unroll
  for (int i = 0; i < 64; i += 4)
    vt[((size_t)kvh * HD + d0 + ty + i) * T_TOK + t0 + tx] = tile[tx][ty + i];
}

// ===== flash attention v5 (R13) + permlane32_swap builtin for PV exchange ===
__device__ __forceinline__ uint32_t pkbf(float a, float b) {
  union { __bf16 h; unsigned short u; } x, y;
  x.h = (__bf16)a;
  y.h = (__bf16)b;
  return (uint32_t)x.u | ((uint32_t)y.u << 16);
}

__global__ __launch_bounds__(256, 2) void flash_attn5(const __bf16* __restrict__ qkv,
                                                      const __bf16* __restrict__ vt,
                                                      __bf16* __restrict__ attn) {
  __shared__ __attribute__((aligned(16))) __bf16 lds[32768];

  const int tid = threadIdx.x;
  const int lane = tid & 63;
  const int wave = tid >> 6;     // 0..3
  const int q5 = lane & 31;
  const int hi = lane >> 5;
  const int yy = blockIdx.x;     // 0..7
  const int kvh = yy >> 1;
  const int h = kvh * 8 + (yy & 1) * 4 + wave;
  const __bf16* Kbase = qkv + KOFF + kvh * HD;
  const __bf16* Vbase = vt + (size_t)kvh * HD * T_TOK;

  const int qt = 63 - (int)blockIdx.y;
  const int qb = qt * 32;
  const int qrow = qb + q5;
  const int nt = (qb + 32 + 63) >> 6;

  const float qscale = 0.088388347648318447f * 1.4426950408889634f;

  bf16x8 qf[8];
  {
    const __bf16* Qp = qkv + (size_t)(qb + q5) * QKV_N + h * HD + hi * 8;
#pragma unroll
    for (int k0 = 0; k0 < 8; ++k0) {
      bf16x8 q = *reinterpret_cast<const bf16x8*>(Qp + k0 * 16);
#pragma unroll
      for (int j = 0; j < 8; ++j) q[j] = (__bf16)((float)q[j] * qscale);
      qf[k0] = q;
    }
  }

  const int kc = (lane & 15) * 16;
  const int vc = (lane & 7) * 16;

#define STAGE5(b, kv00)                                                         \
  do {                                                                          \
    __bf16* kdst = lds + (b) * 8192;                                            \
    __bf16* vdst = lds + 16384 + (b) * 8192;                                    \
    _Pragma("unroll")                                                           \
    for (int i = 0; i < 4; ++i) {                                               \
      int kr = wave * 16 + i * 4 + (lane >> 4);                                 \
      int ksc = (kc ^ ((kr & 15) << 4)) >> 1;                                   \
      GLOAD_LDS16(Kbase + (size_t)((kv00) + kr) * QKV_N + ksc,                  \
                  kdst + (wave * 16 + i * 4) * 128);                            \
      int vr = wave * 32 + i * 8 + (lane >> 3);                                 \
      int vsc = (vc ^ ((vr & 7) << 4)) >> 1;                                    \
      GLOAD_LDS16(Vbase + (size_t)vr * T_TOK + (kv00) + vsc,                    \
                  vdst + (wave * 32 + i * 8) * 64);                             \
    }                                                                           \
  } while (0)

  f32x16 acc0 = {}, acc1 = {}, acc2 = {}, acc3 = {};
  float mrow = -1e30f, lrow = 0.0f;

  STAGE5(0, 0);

  int cur = 0;
  for (int t = 0; t < nt; ++t) {
    const int kv0 = t * 64;
    __builtin_amdgcn_s_barrier();
    __builtin_amdgcn_sched_barrier(0);
    if (t + 1 < nt) {
      STAGE5(cur ^ 1, kv0 + 64);
      asm volatile("s_waitcnt vmcnt(8)" ::: "memory");
    } else {
      asm volatile("s_waitcnt vmcnt(0)" ::: "memory");
    }
    __builtin_amdgcn_s_barrier();
    __builtin_amdgcn_sched_barrier(0);

    const char* Kt = (const char*)(lds + cur * 8192);
    const char* Vt = (const char*)(lds + 16384 + cur * 8192);

    f32x16 st0 = {}, st1 = {};
    __builtin_amdgcn_s_setprio(1);
#pragma unroll
    for (int k0 = 0; k0 < 8; ++k0) {
      int cS = (k0 * 32 + hi * 16) ^ ((q5 & 15) << 4);
      bf16x8 a0 = *reinterpret_cast<const bf16x8*>(Kt + q5 * 256 + cS);
      bf16x8 a1 = *reinterpret_cast<const bf16x8*>(Kt + (32 + q5) * 256 + cS);
      st0 = __builtin_amdgcn_mfma_f32_32x32x16_bf16(a0, qf[k0], st0, 0, 0, 0);
      st1 = __builtin_amdgcn_mfma_f32_32x32x16_bf16(a1, qf[k0], st1, 0, 0, 0);
    }
    __builtin_amdgcn_s_setprio(0);

    if (!(kv0 + 63 <= qb)) {
#pragma unroll
      for (int r = 0; r < 16; ++r) {
        int kp = kv0 + (r & 3) + 8 * (r >> 2) + 4 * hi;
        if (kp > qrow) st0[r] = -1e30f;
        if (kp + 32 > qrow) st1[r] = -1e30f;
      }
    }
    // ---- tree max (R13-proven) ----
    float tm[16];
#pragma unroll
    for (int r = 0; r < 16; ++r) tm[r] = fmaxf(st0[r], st1[r]);
#pragma unroll
    for (int s = 8; s > 0; s >>= 1)
#pragma unroll
      for (int r = 0; r < s; ++r) tm[r] = fmaxf(tm[r], tm[r + s]);
    float mx = fmaxf(tm[0], __shfl_xor(tm[0], 32));
    if (__any(mx > mrow + 8.0f)) {
      float mnew = fmaxf(mrow, mx);
      float corr = exp2f(mrow - mnew);
      lrow *= corr;
      acc0 *= corr; acc1 *= corr; acc2 *= corr; acc3 *= corr;
      mrow = mnew;
    }
    // ---- exp2 + tree sum (R13-proven) ----
    float sv[16];
#pragma unroll
    for (int r = 0; r < 16; ++r) {
      float p0 = exp2f(st0[r] - mrow);
      float p1 = exp2f(st1[r] - mrow);
      sv[r] = p0 + p1;
      st0[r] = p0;
      st1[r] = p1;
    }
#pragma unroll
    for (int s = 8; s > 0; s >>= 1)
#pragma unroll
      for (int r = 0; r < s; ++r) sv[r] += sv[r + s];
    lrow += sv[0] + __shfl_xor(sv[0], 32);

    uint32_t W0[8], W1[8];
#pragma unroll
    for (int m = 0; m < 8; ++m) {
      W0[m] = pkbf(st0[2 * m], st0[2 * m + 1]);
      W1[m] = pkbf(st1[2 * m], st1[2 * m + 1]);
    }

    // ---- PV: P-fragment exchange. permlane32_swap builtin (VALU pipe) when
    // available; operands are distinct values -> no register-coalesce hazard.
#pragma unroll
    for (int ks = 0; ks < 4; ++ks) {
      const int j = 4 * (ks & 1);
      uint32_t wj0, wj1, wj2, wj3;
      if (ks < 2) { wj0 = W0[j]; wj1 = W0[j + 1]; wj2 = W0[j + 2]; wj3 = W0[j + 3]; }
      else        { wj0 = W1[j]; wj1 = W1[j + 1]; wj2 = W1[j + 2]; wj3 = W1[j + 3]; }
      union { uint32_t u[4]; bf16x8 v; } fr;
#if __has_builtin(__builtin_amdgcn_permlane32_swap)
      uint32x2 rA = __builtin_amdgcn_permlane32_swap(wj0, wj2, false, false);
      uint32x2 rB = __builtin_amdgcn_permlane32_swap(wj1, wj3, false, false);
      fr.u[0] = rA[0];   // {wj0_lo, wj2_lo}
      fr.u[1] = rB[0];
      fr.u[2] = rA[1];   // {wj0_hi, wj2_hi}
      fr.u[3] = rB[1];
#else
      const bool hib = (hi != 0);
      uint32_t keepA = hib ? wj2 : wj0;
      uint32_t keepB = hib ? wj3 : wj1;
      uint32_t sendA = hib ? wj0 : wj2;
      uint32_t sendB = hib ? wj1 : wj3;
      uint32_t recvA = (uint32_t)__shfl_xor((int)sendA, 32);
      uint32_t recvB = (uint32_t)__shfl_xor((int)sendB, 32);
      fr.u[0] = hib ? recvA : keepA;
      fr.u[1] = hib ? recvB : keepB;
      fr.u[2] = hib ? keepA : recvA;
      fr.u[3] = hib ? keepB : recvB;
#endif
      const int cV = (ks * 32 + hi * 16) ^ ((q5 & 7) << 4);
      __builtin_amdgcn_s_setprio(1);
      bf16x8 v0 = *reinterpret_cast<const bf16x8*>(Vt + (0 * 32 + q5) * 128 + cV);
      acc0 = __builtin_amdgcn_mfma_f32_32x32x16_bf16(v0, fr.v, acc0, 0, 0, 0);
      bf16x8 v1 = *reinterpret_cast<const bf16x8*>(Vt + (1 * 32 + q5) * 128 + cV);
      acc1 = __builtin_amdgcn_mfma_f32_32x32x16_bf16(v1, fr.v, acc1, 0, 0, 0);
      bf16x8 v2 = *reinterpret_cast<const bf16x8*>(Vt + (2 * 32 + q5) * 128 + cV);
      acc2 = __builtin_amdgcn_mfma_f32_32x32x16_bf16(v2, fr.v, acc2, 0, 0, 0);
      bf16x8 v3 = *reinterpret_cast<const bf16x8*>(Vt + (3 * 32 + q5) * 128 + cV);
      acc3 = __builtin_amdgcn_mfma_f32_32x32x16_bf16(v3, fr.v, acc3, 0, 0, 0);
      __builtin_amdgcn_s_setprio(0);
    }
    cur ^= 1;
  }

  __syncthreads();
  {
    char* ob = (char*)lds + wave * 8192;
    float inv = 1.0f / lrow;
    const int swzE = (q5 & 15) << 4;
#pragma unroll
    for (int dt = 0; dt < 4; ++dt) {
      f32x16 a = dt == 0 ? acc0 : dt == 1 ? acc1 : dt == 2 ? acc2 : acc3;
#pragma unroll
      for (int t4 = 0; t4 < 4; ++t4) {
        uint2 wv;
        wv.x = pkbf(a[4 * t4] * inv, a[4 * t4 + 1] * inv);
        wv.y = pkbf(a[4 * t4 + 2] * inv, a[4 * t4 + 3] * inv);
        int d2 = (dt * 32 + 8 * t4 + 4 * hi) * 2;
        *reinterpret_cast<uint2*>(ob + q5 * 256 + (d2 ^ swzE)) = wv;
      }
    }
#pragma unroll
    for (int rr = 0; rr < 8; ++rr) {
      int idx = rr * 64 + lane;
      int q = idx >> 4;
      int cc = (idx & 15) * 16;
      bf16x8 o = *reinterpret_cast<const bf16x8*>(ob + q * 256 + (cc ^ ((q & 15) << 4)));
      *reinterpret_cast<bf16x8*>(&attn[(size_t)(qb + q) * ATT_N + h * HD + (cc >> 1)]) = o;
    }
  }
}

extern "C" void kernel_launch(void* const* d_in, const int* in_sizes, int n_in,
                              void* d_out, int out_size, void* d_ws, size_t ws_size,
                              hipStream_t stream) {
  const float* hs   = (const float*)d_in[0];
  const int*   pos  = (const int*)d_in[1];
  const float* wqkv = (const float*)d_in[2];
  const float* wo   = (const float*)d_in[3];
  const float* qw   = (const float*)d_in[4];
  const float* kw   = (const float*)d_in[5];
  float* out = (float*)d_out;

  char* p = (char*)d_ws;
  __bf16* hsb   = (__bf16*)p; p += (size_t)T_TOK * HID * 2;
  __bf16* wqkvT = (__bf16*)p; p += (size_t)QKV_N * HID * 2;
  __bf16* woT   = (__bf16*)p; p += (size_t)HID * QSZ * 2;
  __bf16* qkvb  = (__bf16*)p; p += (size_t)T_TOK * QKV_N * 2;
  __bf16* attnb = (__bf16*)p; p += (size_t)T_TOK * QSZ * 2;
  __bf16* vtb   = (__bf16*)p; p += (size_t)NKV * HD * T_TOK * 2;
  float*  ropet = (float*)p;  p += (size_t)T_TOK * HD * 4;
  __bf16* oprt  = (__bf16*)p; p += (size_t)2 * T_TOK * HID * 2;  // bf16 split-K partials

  // 1. fused prep (cast | wqkv^T | wo^T | rope table)
  prep<<<9216, 256, 0, stream>>>(hs, hsb, wqkv, wqkvT, wo, woT, pos, ropet);
  // 2. QKV projection
  gemm_v9<0><<<(QKV_N / 128) * (T_TOK / 128), 256, 0, stream>>>(
      hsb, wqkvT, qkvb, T_TOK, QKV_N, HID, HID, T_TOK / 128, 1);
  // 3. fused RMSNorm+RoPE | V transpose
  postqkv<<<18688, 256, 0, stream>>>(qkvb, vtb, ropet, qw, kw);
  // 4. causal GQA flash attention
  flash_attn5<<<dim3(8, 64), 256, 0, stream>>>(qkvb, vtb, attnb);
  // 5. O projection, split-K=2 (bf16 partials) + reduce
  gemm_v9<1><<<2 * (HID / 128) * (T_TOK / 128), 256, 0, stream>>>(
      attnb, woT, oprt, T_TOK, HID, QSZ, QSZ / 2, T_TOK / 128, 2);
  reduce2_bf<<<(T_TOK * HID / 8 + 255) / 256, 256, 0, stream>>>(
      oprt, out, T_TOK * HID / 8);
}

// Round 18
// 222.380 us; speedup vs baseline: 1.0354x; 1.0016x over previous
//
#include <hip/hip_runtime.h>
#include <hip/hip_bf16.h>

typedef __attribute__((ext_vector_type(8))) __bf16 bf16x8;
typedef __attribute__((ext_vector_type(4))) __bf16 bf16x4;
typedef __attribute__((ext_vector_type(2))) __bf16 bf16x2;
typedef __attribute__((ext_vector_type(4))) float f32x4;
typedef __attribute__((ext_vector_type(16))) float f32x16;
typedef __attribute__((ext_vector_type(2))) unsigned int uint32x2;

#define T_TOK 2048
#define NH 32
#define NKV 4
#define HD 128
#define HID 2048
#define QKV_N 5120   // (32 + 2*4) * 128
#define QSZ 4096     // 32*128
#define KOFF 4096
#define VOFF 4608
#define ATT_N 4096

#define GLOAD_LDS16(g, l)                                              \
  __builtin_amdgcn_global_load_lds(                                    \
      (const __attribute__((address_space(1))) void*)(g),              \
      (__attribute__((address_space(3))) void*)(l), 16, 0, 0)

// ===== fused prep: cast hs | transpose wqkv | transpose wo | rope table ====
__global__ __launch_bounds__(256) void prep(const float* __restrict__ hs,
                                            __bf16* __restrict__ hsb,
                                            const float* __restrict__ wqkv,
                                            __bf16* __restrict__ wqkvT,
                                            const float* __restrict__ wo,
                                            __bf16* __restrict__ woT,
                                            const int* __restrict__ positions,
                                            float* __restrict__ tab) {
  __shared__ __attribute__((aligned(16))) __bf16 tile[64][72];  // [c][r]
  int idx = blockIdx.x;
  if (idx < 4096) {
    int i = idx * 256 + threadIdx.x;
    float4 v = reinterpret_cast<const float4*>(hs)[i];
    bf16x4 o;
    o[0] = (__bf16)v.x; o[1] = (__bf16)v.y; o[2] = (__bf16)v.z; o[3] = (__bf16)v.w;
    reinterpret_cast<bf16x4*>(hsb)[i] = o;
    return;
  }
  idx -= 4096;
  if (idx >= 4608) {
    int j = idx - 4608;
    int t = j * 4 + (threadIdx.x >> 6);
    int d = threadIdx.x & 63;
    float freq = exp2f(-(float)d * 0.20762050593046015f);
    float fr = (float)positions[t] * freq;
    float c, s;
    sincosf(fr, &s, &c);
    tab[t * 128 + d] = c;
    tab[t * 128 + 64 + d] = s;
    return;
  }
  const float* in;
  __bf16* out;
  int R, C, bx, by;
  if (idx < 2560) { in = wqkv; out = wqkvT; R = HID; C = QKV_N; bx = idx % 80; by = idx / 80; }
  else { int j = idx - 2560; in = wo; out = woT; R = QSZ; C = HID; bx = j % 32; by = j / 32; }
  const int c0 = bx * 64;
  const int r0 = by * 64;
  const int ca = (threadIdx.x & 15) * 4;
  const int ra = (threadIdx.x >> 4) * 4;
  float4 v[4];
#pragma unroll
  for (int i = 0; i < 4; ++i)
    v[i] = *reinterpret_cast<const float4*>(&in[(size_t)(r0 + ra + i) * C + c0 + ca]);
#pragma unroll
  for (int j = 0; j < 4; ++j) {
    bf16x4 o;
#pragma unroll
    for (int i = 0; i < 4; ++i) o[i] = (__bf16)(((const float*)&v[i])[j]);
    *reinterpret_cast<bf16x4*>(&tile[ca + j][ra]) = o;
  }
  __syncthreads();
#pragma unroll
  for (int i = 0; i < 2; ++i) {
    int c = i * 32 + (threadIdx.x >> 3);
    int r8 = (threadIdx.x & 7) * 8;
    bf16x8 o = *reinterpret_cast<const bf16x8*>(&tile[c][r8]);
    *reinterpret_cast<bf16x8*>(&out[(size_t)(c0 + c) * R + r0 + r8]) = o;
  }
}

// ====== GEMM v9: C = A*B^T; MODE 0 = bf16 C, MODE 1 = bf16 split-K partials =
template <int MODE>
__global__ __launch_bounds__(256) void gemm_v9(const __bf16* __restrict__ A,
                                               const __bf16* __restrict__ B,
                                               void* __restrict__ Cp,
                                               int M, int N, int Ktot, int KS,
                                               int nby, int nks) {
  __shared__ __attribute__((aligned(16))) __bf16 As[3][128][32];
  __shared__ __attribute__((aligned(16))) __bf16 Bs[3][128][32];
  const int tid = threadIdx.x;
  const int lane = tid & 63;
  const int wave = tid >> 6;
  const int la = lane & 15;
  const int lb = lane >> 4;
  const int wr = (wave >> 1) * 64;
  const int wc = (wave & 1) * 64;

  const int nwg = gridDim.x;
  const int cpx = nwg >> 3;
  const int swz = ((int)blockIdx.x & 7) * cpx + ((int)blockIdx.x >> 3);
  const int ks = swz % nks;
  const int t2 = swz / nks;
  const int by = t2 % nby;
  const int bx = t2 / nby;
  const int rowA0 = by * 128;
  const int rowB0 = bx * 128;
  const int k00 = ks * KS;

  const int srow = wave * 16 + (lane >> 2);
  const int scol = (((lane & 3) * 16) ^ (((lane >> 2) & 3) << 4)) >> 1;
  const __bf16* Asrc0 = &A[(size_t)(rowA0 + srow) * Ktot + k00 + scol];
  const __bf16* Asrc1 = &A[(size_t)(rowA0 + 64 + srow) * Ktot + k00 + scol];
  const __bf16* Bsrc0 = &B[(size_t)(rowB0 + srow) * Ktot + k00 + scol];
  const __bf16* Bsrc1 = &B[(size_t)(rowB0 + 64 + srow) * Ktot + k00 + scol];

#define STAGEG(b, k0)                                            \
  do {                                                           \
    GLOAD_LDS16(Asrc0 + (k0), &As[b][wave * 16][0]);             \
    GLOAD_LDS16(Asrc1 + (k0), &As[b][64 + wave * 16][0]);        \
    GLOAD_LDS16(Bsrc0 + (k0), &Bs[b][wave * 16][0]);             \
    GLOAD_LDS16(Bsrc1 + (k0), &Bs[b][64 + wave * 16][0]);        \
  } while (0)

  f32x4 acc[4][4] = {};

  const int nt = KS >> 5;
  STAGEG(0, 0);
  STAGEG(1, 32);
  asm volatile("s_waitcnt vmcnt(4)" ::: "memory");
  __builtin_amdgcn_s_barrier();
  __builtin_amdgcn_sched_barrier(0);

  const int rdswz = (lb * 16) ^ ((la & 3) << 4);

  int cur = 0, stg = 2;
  for (int t = 0; t < nt; ++t) {
    if (t + 2 < nt) {
      STAGEG(stg, (t + 2) * 32);
    }

    const char* Ab = (const char*)&As[cur][0][0];
    const char* Bb = (const char*)&Bs[cur][0][0];
    bf16x8 af[4], bfr[4];
#pragma unroll
    for (int m = 0; m < 4; ++m)
      af[m] = *reinterpret_cast<const bf16x8*>(Ab + (wr + m * 16 + la) * 64 + rdswz);
#pragma unroll
    for (int n = 0; n < 4; ++n)
      bfr[n] = *reinterpret_cast<const bf16x8*>(Bb + (wc + n * 16 + la) * 64 + rdswz);
    __builtin_amdgcn_s_setprio(1);
#pragma unroll
    for (int m = 0; m < 4; ++m)
#pragma unroll
      for (int n = 0; n < 4; ++n)
        acc[m][n] = __builtin_amdgcn_mfma_f32_16x16x32_bf16(af[m], bfr[n], acc[m][n], 0, 0, 0);
    __builtin_amdgcn_s_setprio(0);

    const int rem = nt - 1 - t;
    if (rem >= 2) {
      asm volatile("s_waitcnt vmcnt(4)" ::: "memory");
    } else if (rem == 1) {
      asm volatile("s_waitcnt vmcnt(0)" ::: "memory");
    }
    if (rem) {
      __builtin_amdgcn_sched_barrier(0);
      __builtin_amdgcn_s_barrier();
      __builtin_amdgcn_sched_barrier(0);
    }
    cur = (cur == 2) ? 0 : cur + 1;
    stg = (stg == 2) ? 0 : stg + 1;
  }
#undef STAGEG

#pragma unroll
  for (int m = 0; m < 4; ++m) {
#pragma unroll
    for (int n = 0; n < 4; ++n) {
#pragma unroll
      for (int r = 0; r < 4; ++r) {
        int row = rowA0 + wr + m * 16 + lb * 4 + r;
        int col = rowB0 + wc + n * 16 + la;
        if (MODE == 1) {
          __bf16* pp = (__bf16*)Cp + (size_t)ks * M * N;
          pp[(size_t)row * N + col] = (__bf16)acc[m][n][r];
        } else {
          reinterpret_cast<__bf16*>(Cp)[(size_t)row * N + col] = (__bf16)acc[m][n][r];
        }
      }
    }
  }
}

// ---- split-K reduce: out[i] = (f32)p0[i] + (f32)p1[i], bf16 partials ------
__global__ __launch_bounds__(256) void reduce2_bf(const __bf16* __restrict__ pp,
                                                  float* __restrict__ out, int n8) {
  int i = blockIdx.x * 256 + threadIdx.x;
  if (i < n8) {
    bf16x8 a = reinterpret_cast<const bf16x8*>(pp)[i];
    bf16x8 b = reinterpret_cast<const bf16x8*>(pp + (size_t)HID * T_TOK)[i];
    float4 o0, o1;
    o0.x = (float)a[0] + (float)b[0];
    o0.y = (float)a[1] + (float)b[1];
    o0.z = (float)a[2] + (float)b[2];
    o0.w = (float)a[3] + (float)b[3];
    o1.x = (float)a[4] + (float)b[4];
    o1.y = (float)a[5] + (float)b[5];
    o1.z = (float)a[6] + (float)b[6];
    o1.w = (float)a[7] + (float)b[7];
    reinterpret_cast<float4*>(out)[2 * i] = o0;
    reinterpret_cast<float4*>(out)[2 * i + 1] = o1;
  }
}

// ===== fused post-QKV: RMSNorm+RoPE (q,k) | V transpose =====================
__global__ __launch_bounds__(256) void postqkv(__bf16* __restrict__ qkv,
                                               __bf16* __restrict__ vt,
                                               const float* __restrict__ tab,
                                               const float* __restrict__ qw,
                                               const float* __restrict__ kw) {
  __shared__ __bf16 tile[64][72];
  int idx = blockIdx.x;
  if (idx < 18432) {
    const int t = idx & 2047;
    const int hg = idx >> 11;
    const int wave = threadIdx.x >> 6;
    const int lane = threadIdx.x & 63;
    const int head = hg * 4 + wave;
    const bool is_q = head < NH;
    const int col = is_q ? head * HD : KOFF + (head - NH) * HD;
    __bf16* row = qkv + (size_t)t * QKV_N + col;

    bf16x2 v = *reinterpret_cast<const bf16x2*>(&row[lane * 2]);
    float x0 = (float)v[0], x1 = (float)v[1];
    float ss = x0 * x0 + x1 * x1;
#pragma unroll
    for (int mm = 1; mm < 64; mm <<= 1) ss += __shfl_xor(ss, mm);
    float sc = rsqrtf(ss * (1.0f / 128.0f) + 1e-6f);
    const float* wv = is_q ? qw : kw;
    float y0 = x0 * sc * wv[lane * 2];
    float y1 = x1 * sc * wv[lane * 2 + 1];
    float o0 = __shfl_xor(y0, 32);
    float o1 = __shfl_xor(y1, 32);
    const int dbase = (lane & 31) * 2;
    float c0 = tab[t * 128 + dbase], c1 = tab[t * 128 + dbase + 1];
    float s0 = tab[t * 128 + 64 + dbase], s1 = tab[t * 128 + 64 + dbase + 1];
    float r0, r1;
    if (lane < 32) { r0 = y0 * c0 - o0 * s0; r1 = y1 * c1 - o1 * s1; }
    else           { r0 = y0 * c0 + o0 * s0; r1 = y1 * c1 + o1 * s1; }
    bf16x2 ov;
    ov[0] = (__bf16)r0;
    ov[1] = (__bf16)r1;
    *reinterpret_cast<bf16x2*>(&row[lane * 2]) = ov;
    return;
  }
  const int j = idx - 18432;
  const int t0 = (j & 31) * 64;
  const int d0 = ((j >> 5) & 1) * 64;
  const int kvh = j >> 6;
  const int tx = threadIdx.x & 63;
  const int ty = threadIdx.x >> 6;
#pragma unroll
  for (int i = 0; i < 64; i += 4)
    tile[ty + i][tx] = qkv[(size_t)(t0 + ty + i) * QKV_N + VOFF + kvh * HD + d0 + tx];
  __syncthreads();
#pragma unroll
  for (int i = 0; i < 64; i += 4)
    vt[((size_t)kvh * HD + d0 + ty + i) * T_TOK + t0 + tx] = tile[tx][ty + i];
}

// ===== flash attention v5 (R16-verified): permlane only for PV exchange =====
__device__ __forceinline__ uint32_t pkbf(float a, float b) {
  union { __bf16 h; unsigned short u; } x, y;
  x.h = (__bf16)a;
  y.h = (__bf16)b;
  return (uint32_t)x.u | ((uint32_t)y.u << 16);
}

__global__ __launch_bounds__(256, 2) void flash_attn5(const __bf16* __restrict__ qkv,
                                                      const __bf16* __restrict__ vt,
                                                      __bf16* __restrict__ attn) {
  __shared__ __attribute__((aligned(16))) __bf16 lds[32768];

  const int tid = threadIdx.x;
  const int lane = tid & 63;
  const int wave = tid >> 6;     // 0..3
  const int q5 = lane & 31;
  const int hi = lane >> 5;
  const int yy = blockIdx.x;     // 0..7
  const int kvh = yy >> 1;
  const int h = kvh * 8 + (yy & 1) * 4 + wave;
  const __bf16* Kbase = qkv + KOFF + kvh * HD;
  const __bf16* Vbase = vt + (size_t)kvh * HD * T_TOK;

  const int qt = 63 - (int)blockIdx.y;
  const int qb = qt * 32;
  const int qrow = qb + q5;
  const int nt = (qb + 32 + 63) >> 6;

  const float qscale = 0.088388347648318447f * 1.4426950408889634f;

  bf16x8 qf[8];
  {
    const __bf16* Qp = qkv + (size_t)(qb + q5) * QKV_N + h * HD + hi * 8;
#pragma unroll
    for (int k0 = 0; k0 < 8; ++k0) {
      bf16x8 q = *reinterpret_cast<const bf16x8*>(Qp + k0 * 16);
#pragma unroll
      for (int j = 0; j < 8; ++j) q[j] = (__bf16)((float)q[j] * qscale);
      qf[k0] = q;
    }
  }

  const int kc = (lane & 15) * 16;
  const int vc = (lane & 7) * 16;

#define STAGE5(b, kv00)                                                         \
  do {                                                                          \
    __bf16* kdst = lds + (b) * 8192;                                            \
    __bf16* vdst = lds + 16384 + (b) * 8192;                                    \
    _Pragma("unroll")                                                           \
    for (int i = 0; i < 4; ++i) {                                               \
      int kr = wave * 16 + i * 4 + (lane >> 4);                                 \
      int ksc = (kc ^ ((kr & 15) << 4)) >> 1;                                   \
      GLOAD_LDS16(Kbase + (size_t)((kv00) + kr) * QKV_N + ksc,                  \
                  kdst + (wave * 16 + i * 4) * 128);                            \
      int vr = wave * 32 + i * 8 + (lane >> 3);                                 \
      int vsc = (vc ^ ((vr & 7) << 4)) >> 1;                                    \
      GLOAD_LDS16(Vbase + (size_t)vr * T_TOK + (kv00) + vsc,                    \
                  vdst + (wave * 32 + i * 8) * 64);                             \
    }                                                                           \
  } while (0)

  f32x16 acc0 = {}, acc1 = {}, acc2 = {}, acc3 = {};
  float mrow = -1e30f, lrow = 0.0f;

  STAGE5(0, 0);

  int cur = 0;
  for (int t = 0; t < nt; ++t) {
    const int kv0 = t * 64;
    __builtin_amdgcn_s_barrier();
    __builtin_amdgcn_sched_barrier(0);
    if (t + 1 < nt) {
      STAGE5(cur ^ 1, kv0 + 64);
      asm volatile("s_waitcnt vmcnt(8)" ::: "memory");
    } else {
      asm volatile("s_waitcnt vmcnt(0)" ::: "memory");
    }
    __builtin_amdgcn_s_barrier();
    __builtin_amdgcn_sched_barrier(0);

    const char* Kt = (const char*)(lds + cur * 8192);
    const char* Vt = (const char*)(lds + 16384 + cur * 8192);

    f32x16 st0 = {}, st1 = {};
    __builtin_amdgcn_s_setprio(1);
#pragma unroll
    for (int k0 = 0; k0 < 8; ++k0) {
      int cS = (k0 * 32 + hi * 16) ^ ((q5 & 15) << 4);
      bf16x8 a0 = *reinterpret_cast<const bf16x8*>(Kt + q5 * 256 + cS);
      bf16x8 a1 = *reinterpret_cast<const bf16x8*>(Kt + (32 + q5) * 256 + cS);
      st0 = __builtin_amdgcn_mfma_f32_32x32x16_bf16(a0, qf[k0], st0, 0, 0, 0);
      st1 = __builtin_amdgcn_mfma_f32_32x32x16_bf16(a1, qf[k0], st1, 0, 0, 0);
    }
    __builtin_amdgcn_s_setprio(0);

    if (!(kv0 + 63 <= qb)) {
#pragma unroll
      for (int r = 0; r < 16; ++r) {
        int kp = kv0 + (r & 3) + 8 * (r >> 2) + 4 * hi;
        if (kp > qrow) st0[r] = -1e30f;
        if (kp + 32 > qrow) st1[r] = -1e30f;
      }
    }
    // ---- tree max (R13/R16-proven shfl cross-half) ----
    float tm[16];
#pragma unroll
    for (int r = 0; r < 16; ++r) tm[r] = fmaxf(st0[r], st1[r]);
#pragma unroll
    for (int s = 8; s > 0; s >>= 1)
#pragma unroll
      for (int r = 0; r < s; ++r) tm[r] = fmaxf(tm[r], tm[r + s]);
    float mx = fmaxf(tm[0], __shfl_xor(tm[0], 32));
    if (__any(mx > mrow + 8.0f)) {
      float mnew = fmaxf(mrow, mx);
      float corr = exp2f(mrow - mnew);
      lrow *= corr;
      acc0 *= corr; acc1 *= corr; acc2 *= corr; acc3 *= corr;
      mrow = mnew;
    }
    // ---- exp2 + tree sum ----
    float sv[16];
#pragma unroll
    for (int r = 0; r < 16; ++r) {
      float p0 = exp2f(st0[r] - mrow);
      float p1 = exp2f(st1[r] - mrow);
      sv[r] = p0 + p1;
      st0[r] = p0;
      st1[r] = p1;
    }
#pragma unroll
    for (int s = 8; s > 0; s >>= 1)
#pragma unroll
      for (int r = 0; r < s; ++r) sv[r] += sv[r + s];
    lrow += sv[0] + __shfl_xor(sv[0], 32);

    uint32_t W0[8], W1[8];
#pragma unroll
    for (int m = 0; m < 8; ++m) {
      W0[m] = pkbf(st0[2 * m], st0[2 * m + 1]);
      W1[m] = pkbf(st1[2 * m], st1[2 * m + 1]);
    }

    // ---- PV: P-fragment exchange via permlane32_swap (distinct operands;
    // R16-verified). Fallback: shfl path. ----
#pragma unroll
    for (int ks = 0; ks < 4; ++ks) {
      const int j = 4 * (ks & 1);
      uint32_t wj0, wj1, wj2, wj3;
      if (ks < 2) { wj0 = W0[j]; wj1 = W0[j + 1]; wj2 = W0[j + 2]; wj3 = W0[j + 3]; }
      else        { wj0 = W1[j]; wj1 = W1[j + 1]; wj2 = W1[j + 2]; wj3 = W1[j + 3]; }
      union { uint32_t u[4]; bf16x8 v; } fr;
#if __has_builtin(__builtin_amdgcn_permlane32_swap)
      uint32x2 rA = __builtin_amdgcn_permlane32_swap(wj0, wj2, false, false);
      uint32x2 rB = __builtin_amdgcn_permlane32_swap(wj1, wj3, false, false);
      fr.u[0] = rA[0];   // {wj0_lo, wj2_lo}
      fr.u[1] = rB[0];
      fr.u[2] = rA[1];   // {wj0_hi, wj2_hi}
      fr.u[3] = rB[1];
#else
      const bool hib = (hi != 0);
      uint32_t keepA = hib ? wj2 : wj0;
      uint32_t keepB = hib ? wj3 : wj1;
      uint32_t sendA = hib ? wj0 : wj2;
      uint32_t sendB = hib ? wj1 : wj3;
      uint32_t recvA = (uint32_t)__shfl_xor((int)sendA, 32);
      uint32_t recvB = (uint32_t)__shfl_xor((int)sendB, 32);
      fr.u[0] = hib ? recvA : keepA;
      fr.u[1] = hib ? recvB : keepB;
      fr.u[2] = hib ? keepA : recvA;
      fr.u[3] = hib ? keepB : recvB;
#endif
      const int cV = (ks * 32 + hi * 16) ^ ((q5 & 7) << 4);
      __builtin_amdgcn_s_setprio(1);
      bf16x8 v0 = *reinterpret_cast<const bf16x8*>(Vt + (0 * 32 + q5) * 128 + cV);
      acc0 = __builtin_amdgcn_mfma_f32_32x32x16_bf16(v0, fr.v, acc0, 0, 0, 0);
      bf16x8 v1 = *reinterpret_cast<const bf16x8*>(Vt + (1 * 32 + q5) * 128 + cV);
      acc1 = __builtin_amdgcn_mfma_f32_32x32x16_bf16(v1, fr.v, acc1, 0, 0, 0);
      bf16x8 v2 = *reinterpret_cast<const bf16x8*>(Vt + (2 * 32 + q5) * 128 + cV);
      acc2 = __builtin_amdgcn_mfma_f32_32x32x16_bf16(v2, fr.v, acc2, 0, 0, 0);
      bf16x8 v3 = *reinterpret_cast<const bf16x8*>(Vt + (3 * 32 + q5) * 128 + cV);
      acc3 = __builtin_amdgcn_mfma_f32_32x32x16_bf16(v3, fr.v, acc3, 0, 0, 0);
      __builtin_amdgcn_s_setprio(0);
    }
    cur ^= 1;
  }

  __syncthreads();
  {
    char* ob = (char*)lds + wave * 8192;
    float inv = 1.0f / lrow;
    const int swzE = (q5 & 15) << 4;
#pragma unroll
    for (int dt = 0; dt < 4; ++dt) {
      f32x16 a = dt == 0 ? acc0 : dt == 1 ? acc1 : dt == 2 ? acc2 : acc3;
#pragma unroll
      for (int t4 = 0; t4 < 4; ++t4) {
        uint2 wv;
        wv.x = pkbf(a[4 * t4] * inv, a[4 * t4 + 1] * inv);
        wv.y = pkbf(a[4 * t4 + 2] * inv, a[4 * t4 + 3] * inv);
        int d2 = (dt * 32 + 8 * t4 + 4 * hi) * 2;
        *reinterpret_cast<uint2*>(ob + q5 * 256 + (d2 ^ swzE)) = wv;
      }
    }
#pragma unroll
    for (int rr = 0; rr < 8; ++rr) {
      int idx = rr * 64 + lane;
      int q = idx >> 4;
      int cc = (idx & 15) * 16;
      bf16x8 o = *reinterpret_cast<const bf16x8*>(ob + q * 256 + (cc ^ ((q & 15) << 4)));
      *reinterpret_cast<bf16x8*>(&attn[(size_t)(qb + q) * ATT_N + h * HD + (cc >> 1)]) = o;
    }
  }
}

extern "C" void kernel_launch(void* const* d_in, const int* in_sizes, int n_in,
                              void* d_out, int out_size, void* d_ws, size_t ws_size,
                              hipStream_t stream) {
  const float* hs   = (const float*)d_in[0];
  const int*   pos  = (const int*)d_in[1];
  const float* wqkv = (const float*)d_in[2];
  const float* wo   = (const float*)d_in[3];
  const float* qw   = (const float*)d_in[4];
  const float* kw   = (const float*)d_in[5];
  float* out = (float*)d_out;

  char* p = (char*)d_ws;
  __bf16* hsb   = (__bf16*)p; p += (size_t)T_TOK * HID * 2;
  __bf16* wqkvT = (__bf16*)p; p += (size_t)QKV_N * HID * 2;
  __bf16* woT   = (__bf16*)p; p += (size_t)HID * QSZ * 2;
  __bf16* qkvb  = (__bf16*)p; p += (size_t)T_TOK * QKV_N * 2;
  __bf16* attnb = (__bf16*)p; p += (size_t)T_TOK * QSZ * 2;
  __bf16* vtb   = (__bf16*)p; p += (size_t)NKV * HD * T_TOK * 2;
  float*  ropet = (float*)p;  p += (size_t)T_TOK * HD * 4;
  __bf16* oprt  = (__bf16*)p; p += (size_t)2 * T_TOK * HID * 2;  // bf16 split-K partials

  // 1. fused prep (cast | wqkv^T | wo^T | rope table)
  prep<<<9216, 256, 0, stream>>>(hs, hsb, wqkv, wqkvT, wo, woT, pos, ropet);
  // 2. QKV projection
  gemm_v9<0><<<(QKV_N / 128) * (T_TOK / 128), 256, 0, stream>>>(
      hsb, wqkvT, qkvb, T_TOK, QKV_N, HID, HID, T_TOK / 128, 1);
  // 3. fused RMSNorm+RoPE | V transpose
  postqkv<<<18688, 256, 0, stream>>>(qkvb, vtb, ropet, qw, kw);
  // 4. causal GQA flash attention
  flash_attn5<<<dim3(8, 64), 256, 0, stream>>>(qkvb, vtb, attnb);
  // 5. O projection, split-K=2 (bf16 partials) + reduce
  gemm_v9<1><<<2 * (HID / 128) * (T_TOK / 128), 256, 0, stream>>>(
      attnb, woT, oprt, T_TOK, HID, QSZ, QSZ / 2, T_TOK / 128, 2);
  reduce2_bf<<<(T_TOK * HID / 8 + 255) / 256, 256, 0, stream>>>(
      oprt, out, T_TOK * HID / 8);
}